// Round 4
// baseline (358.112 us; speedup 1.0000x reference)
//
#include <hip/hip_runtime.h>
#include <hip/hip_bf16.h>
#include <math.h>

#define B_ 2
#define H_ 12
#define S_ 1024
#define D_ 128
#define BH_ (B_ * H_)
#define SCALE 0.08838834764831843f

#define QPAD 16
#define QROWS (S_ + QPAD)          /* 1040 */

/* merged prepass grid segmentation */
#define NB_KH   768                /* 24 bh * 32 k-tiles */
#define NB_QP   3120               /* 24*1040*128 / 1024 */
#define NB_VT   3072               /* 24*32*4 */
#define NB_CORR 384                /* 24*16 */
#define NB_PREP (NB_KH + NB_QP + NB_VT + NB_CORR)

typedef __attribute__((ext_vector_type(8))) short short8;
typedef __attribute__((ext_vector_type(4))) float floatx4;

__device__ __forceinline__ unsigned short f2b(float f) {
    return __builtin_bit_cast(unsigned short, __float2bfloat16(f));
}

// ---- merged prepass ---------------------------------------------------------
// KH: Khat fragment-major. Block (bh*32+kt) is 24576 ushorts: [c24][nt2][ln64][e8]
//     Khat[k=kt*32+nt*16+(ln&15)][col=c*32+(ln>>4)*8+e],
//     Khat[k][i*128+d] = sum_j W[h][i][j]*SCALE * K[k+j-5][d].
//     K tile staged in LDS; fragments assembled in LDS; coalesced 16B stores.
// QP: Q -> bf16 row-major, 16 zero rows of top padding.
// VT: VhF[bh*32+kt][nd8][ln64][e8] = V (sigma-permuted for swapped-MFMA PV).
// CORR: Corr[bh][q][d] = sum_{i,j: j-i>d} Ws[i,j]*(Q[q-5+i].K[q-5+i+(j-i-d)])
__global__ __launch_bounds__(256) void prep_kernel(
    const float* __restrict__ Q, const float* __restrict__ K,
    const float* __restrict__ V, const float* __restrict__ W,
    unsigned short* __restrict__ Qp, unsigned short* __restrict__ KhF,
    unsigned short* __restrict__ VhF, float* __restrict__ Corr)
{
    __shared__ __align__(16) union {
        struct { float kld[42][128]; unsigned short khs[24576]; } kh;  /* 70656 B */
        float vt_ls[32][33];
        float band[69][16];
    } sm;
    const int blk = blockIdx.x;
    const int tid = threadIdx.x;

    if (blk < NB_KH) {
        const int bh = blk >> 5, kt = blk & 31;
        const int h = bh % H_;
        const int k0 = kt * 32;
        // stage K rows k0-5 .. k0+36 (zero-padded OOB)
        for (int p = tid; p < 42 * 32; p += 256) {
            const int r = p >> 5, c4 = (p & 31) * 4;
            const int gk = k0 - 5 + r;
            float4 v = make_float4(0.f, 0.f, 0.f, 0.f);
            if (gk >= 0 && gk < S_)
                v = *(const float4*)(K + ((size_t)bh * S_ + gk) * D_ + c4);
            *(float4*)&sm.kh.kld[r][c4] = v;
        }
        __syncthreads();
        const float* Wh = W + h * 66;
        #pragma unroll
        for (int it = 0; it < 4; ++it) {
            const int p = tid + it * 256;
            const int r = p >> 5;             // k-row in tile
            const int d0 = (p & 31) * 4;      // col group
            float a[6][4];
            #pragma unroll
            for (int i = 0; i < 6; ++i)
                #pragma unroll
                for (int t = 0; t < 4; ++t) a[i][t] = 0.f;
            #pragma unroll
            for (int j = 0; j < 11; ++j) {
                const float4 kv = *(const float4*)&sm.kh.kld[r + j][d0];
                #pragma unroll
                for (int i = 0; i < 6; ++i) {
                    const float w = Wh[i * 11 + j];
                    a[i][0] += w * kv.x; a[i][1] += w * kv.y;
                    a[i][2] += w * kv.z; a[i][3] += w * kv.w;
                }
            }
            const int nt = r >> 4;
            const int ln2 = (((d0 & 31) >> 3) << 4) | (r & 15);
            const int e0 = d0 & 7;
            const int cc = d0 >> 5;
            #pragma unroll
            for (int i = 0; i < 6; ++i) {
                const int c = i * 4 + cc;
                ushort4 o;
                o.x = f2b(a[i][0] * SCALE); o.y = f2b(a[i][1] * SCALE);
                o.z = f2b(a[i][2] * SCALE); o.w = f2b(a[i][3] * SCALE);
                *(ushort4*)&sm.kh.khs[(size_t)((c * 2 + nt) * 64 + ln2) * 8 + e0] = o;
            }
        }
        __syncthreads();
        const size_t obase = (size_t)blk * 24576;   // blk == bh*32+kt
        #pragma unroll
        for (int itc = 0; itc < 12; ++itc) {
            const int off = (tid + itc * 256) * 8;
            *(short8*)(KhF + obase + off) = *(const short8*)&sm.kh.khs[off];
        }
    } else if (blk < NB_KH + NB_QP) {
        const int idx = (blk - NB_KH) * 256 + tid;
        const size_t e0 = (size_t)idx * 4;
        const int bh = (int)(e0 / ((size_t)QROWS * D_));
        const int rem = (int)(e0 - (size_t)bh * QROWS * D_);
        const int r = rem / D_;
        const int d = rem - r * D_;
        const int sr = r - QPAD;
        float4 v = make_float4(0.f, 0.f, 0.f, 0.f);
        if (sr >= 0 && sr < S_)
            v = *(const float4*)(Q + ((size_t)bh * S_ + sr) * D_ + d);
        ushort4 o; o.x = f2b(v.x); o.y = f2b(v.y); o.z = f2b(v.z); o.w = f2b(v.w);
        *(ushort4*)(Qp + ((size_t)bh * QROWS + r) * D_ + d) = o;
    } else if (blk < NB_KH + NB_QP + NB_VT) {
        const int b2 = blk - (NB_KH + NB_QP);
        const int dt = b2 & 3, ktl = (b2 >> 2) & 31, bh = b2 >> 7;
        const int lk = tid >> 3, ld = (tid & 7) * 4;
        const float4 v4 = *(const float4*)(V + ((size_t)bh * S_ + ktl * 32 + lk) * D_ + dt * 32 + ld);
        sm.vt_ls[lk][ld + 0] = v4.x; sm.vt_ls[lk][ld + 1] = v4.y;
        sm.vt_ls[lk][ld + 2] = v4.z; sm.vt_ls[lk][ld + 3] = v4.w;
        __syncthreads();
        const int lk2 = tid >> 3, lc = (tid & 7) * 4;
        const int pb = ((lc >> 3) << 2) | (((lc >> 2) & 1) << 4);   // sigma
        const int d = dt * 32 + lk2;
        const int nd = d >> 4, l15v = d & 15;
        ushort4 o;
        o.x = f2b(sm.vt_ls[pb + 0][lk2]); o.y = f2b(sm.vt_ls[pb + 1][lk2]);
        o.z = f2b(sm.vt_ls[pb + 2][lk2]); o.w = f2b(sm.vt_ls[pb + 3][lk2]);
        const size_t addr = ((size_t)((bh * 32 + ktl) * 8 + nd) * 64
                             + (lc >> 3) * 16 + l15v) * 8 + (lc & 7);
        *(ushort4*)(VhF + addr) = o;
    } else {
        const int cb = blk - (NB_KH + NB_QP + NB_VT);
        const int bh = cb >> 4, q0c = (cb & 15) * 64;
        const int h = bh % H_;
        for (int s = tid; s < 69 * 16; s += 256) {
            const int r = s >> 4, dsl = s & 15;
            float v = 0.f;
            if (dsl < 10) {
                const int qp = q0c - 5 + r, delta = dsl + 1;
                if (qp >= 0 && qp + delta < S_) {
                    const float4* qr = (const float4*)(Q + ((size_t)bh * S_ + qp) * D_);
                    const float4* kr = (const float4*)(K + ((size_t)bh * S_ + qp + delta) * D_);
                    #pragma unroll 8
                    for (int c = 0; c < 32; ++c) {
                        const float4 a = qr[c], b = kr[c];
                        v += a.x * b.x + a.y * b.y + a.z * b.z + a.w * b.w;
                    }
                }
            }
            sm.band[r][dsl] = v;
        }
        __syncthreads();
        for (int e = tid; e < 64 * 16; e += 256) {
            const int ql = e >> 4, d = e & 15;
            float v = 0.f;
            if (d <= 10) {
                for (int i2 = 0; i2 < 6; ++i2)
                    for (int j = i2 + d + 1; j < 11; ++j)
                        v += W[h * 66 + i2 * 11 + j] * SCALE * sm.band[ql + i2][j - i2 - d - 1];
            }
            Corr[((size_t)bh << 14) + ((size_t)(q0c + ql) << 4) + d] = v;
        }
    }
}

// ---- main fused kernel ------------------------------------------------------
// Grid 384 = 24 bh x 8 qb x 2 k-splits. Block = 4 waves x 32 q-rows (TQ=128).
// No-max softmax (logits bounded) -> partials are plain sums; merge kernel
// combines the two k-splits. Khat half-tiles double-buffered via
// global_load_lds (48 KiB LDS); Q fragments streamed per half from L2.
__global__ __launch_bounds__(256, 2) void conv_attn_mfma(
    const unsigned short* __restrict__ Qp,   // [24][1040][128] bf16
    const unsigned short* __restrict__ KhF,  // fragment-major Khat
    const unsigned short* __restrict__ VhF,  // fragment-major permuted V
    const float* __restrict__ Corr,          // [24][1024][16]  f32
    float* __restrict__ O,                   // ks=0 partial (also final out)
    float* __restrict__ Op1,                 // ks=1 partial
    float* __restrict__ L0, float* __restrict__ L1)  // [24*1024] row sums
{
    __shared__ __align__(16) unsigned short kb[2][12288];   // 2 x 24 KiB halves

    const int tid = threadIdx.x;
    const int wv = tid >> 6;
    const int ln = tid & 63;
    const int l15 = ln & 15;
    const int qd = ln >> 4;

    const int bid = blockIdx.x;
    const int wg = (bid & 7) * 48 + (bid >> 3);   // XCD-contiguous
    const int bh = wg / 16;
    const int r16 = wg - bh * 16;
    const int qb = 7 - (r16 >> 1);                // heavy q-blocks first
    const int ks = r16 & 1;

    const int qw0 = qb * 128 + wv * 32;           // this wave's first q-row
    const int ktw = 4 * qb + wv;                  // this wave's last k-tile
    const int klo = ks * (2 * qb + 2);            // k-split range start
    const int Hmax = 4 * qb + 4;                  // 2 halves x (2qb+2) tiles

    const unsigned short* Khb = KhF + (size_t)(bh * 32) * 24576;
    const unsigned short* Vhb = VhF + (size_t)(bh * 32) * 4096 + ln * 8;
    const float* Cb = Corr + ((size_t)bh << 14);
    const unsigned short* qbase = Qp + ((size_t)bh * QROWS + qw0 + 11 + l15) * D_ + qd * 8;

#define STAGE(bi, Hn)                                                           \
    {                                                                           \
        const int _kt = klo + ((Hn) >> 1);                                      \
        const unsigned short* _s = Khb + ((size_t)_kt * 2 + ((Hn) & 1)) * 12288 \
                                   + wv * 3072 + ln * 8;                        \
        unsigned short* _d = &kb[bi][wv * 3072];                                \
        _Pragma("unroll")                                                       \
        for (int _g = 0; _g < 6; ++_g)                                          \
            __builtin_amdgcn_global_load_lds(                                   \
                (const __attribute__((address_space(1))) void*)(_s + _g * 512), \
                (__attribute__((address_space(3))) void*)(_d + _g * 512),       \
                16, 0, 0);                                                      \
    }

    floatx4 acc[2][8];
    #pragma unroll
    for (int mt = 0; mt < 2; ++mt)
        #pragma unroll
        for (int nd = 0; nd < 8; ++nd)
            acc[mt][nd] = (floatx4){0.f, 0.f, 0.f, 0.f};
    float l_run[2] = {0.f, 0.f};
    floatx4 sc_[2][2];      // [nt][mt]: rows=k (qd*4+rg), cols=q (l15)
    short8 vf[8];

    STAGE(0, 0);
    __syncthreads();

    for (int H = 0; H < Hmax; ++H) {
        const int kt = klo + (H >> 1);
        const int h = H & 1;
        if (H + 1 < Hmax) STAGE((H + 1) & 1, H + 1);

        if (kt <= ktw) {
            const unsigned short* A = &kb[H & 1][ln * 8];

            // Q B-fragments for this half's 3 taps (streamed, L2-resident)
            short8 bq[2][3][4];
            #pragma unroll
            for (int mt = 0; mt < 2; ++mt)
                #pragma unroll
                for (int ii = 0; ii < 3; ++ii)
                    #pragma unroll
                    for (int kc = 0; kc < 4; ++kc)
                        bq[mt][ii][kc] = *(const short8*)(
                            qbase + (size_t)(mt * 16 + 3 * h + ii) * D_ + kc * 32);

            if (h == 0) {
                #pragma unroll
                for (int nd = 0; nd < 8; ++nd)
                    vf[nd] = *(const short8*)(Vhb + (size_t)kt * 4096 + nd * 512);
                #pragma unroll
                for (int nt = 0; nt < 2; ++nt)
                    #pragma unroll
                    for (int mt = 0; mt < 2; ++mt)
                        sc_[nt][mt] = (floatx4){0.f, 0.f, 0.f, 0.f};
            }

            #pragma unroll
            for (int cl = 0; cl < 12; ++cl) {
                const short8 a0 = *(const short8*)(A + cl * 1024);
                const short8 a1 = *(const short8*)(A + cl * 1024 + 512);
                const short8 b0 = bq[0][cl >> 2][cl & 3];
                const short8 b1 = bq[1][cl >> 2][cl & 3];
                sc_[0][0] = __builtin_amdgcn_mfma_f32_16x16x32_bf16(a0, b0, sc_[0][0], 0, 0, 0);
                sc_[0][1] = __builtin_amdgcn_mfma_f32_16x16x32_bf16(a0, b1, sc_[0][1], 0, 0, 0);
                sc_[1][0] = __builtin_amdgcn_mfma_f32_16x16x32_bf16(a1, b0, sc_[1][0], 0, 0, 0);
                sc_[1][1] = __builtin_amdgcn_mfma_f32_16x16x32_bf16(a1, b1, sc_[1][1], 0, 0, 0);
            }

            if (h == 1) {
                const int k0 = kt * 32;
                const bool need_corr = (kt >= ktw - 1);
                short8 pfrag[2];
                #pragma unroll
                for (int mt = 0; mt < 2; ++mt) {
                    const int qrow = qw0 + mt * 16 + l15;
                    float sum = 0.f;
                    short8 pbv;
                    #pragma unroll
                    for (int nt = 0; nt < 2; ++nt)
                        #pragma unroll
                        for (int rg = 0; rg < 4; ++rg) {
                            const int kcol = k0 + nt * 16 + qd * 4 + rg;
                            float v = sc_[nt][mt][rg];
                            if (need_corr) {
                                const int dd = qrow - kcol;
                                if (dd >= 0 && dd <= 10) v -= Cb[(qrow << 4) + dd];
                            }
                            const float p = (kcol <= qrow) ? __expf(v) : 0.f;
                            sum += p;
                            pbv[nt * 4 + rg] = (short)f2b(p);
                        }
                    sum += __shfl_xor(sum, 16);
                    sum += __shfl_xor(sum, 32);
                    l_run[mt] += sum;
                    pfrag[mt] = pbv;
                }
                #pragma unroll
                for (int nd = 0; nd < 8; ++nd)
                    #pragma unroll
                    for (int mt = 0; mt < 2; ++mt)
                        acc[mt][nd] = __builtin_amdgcn_mfma_f32_16x16x32_bf16(pfrag[mt], vf[nd], acc[mt][nd], 0, 0, 0);
            }
        }
        __syncthreads();
    }

    // ---- write this k-split's partial (unnormalized) -----------------------
    float* Ob = ks ? Op1 : O;
    float* Lb = ks ? L1 : L0;
    if (qd == 0) {
        Lb[bh * S_ + qw0 + l15] = l_run[0];
        Lb[bh * S_ + qw0 + 16 + l15] = l_run[1];
    }
    #pragma unroll
    for (int mt = 0; mt < 2; ++mt)
        #pragma unroll
        for (int rg = 0; rg < 4; ++rg) {
            const int row = qw0 + mt * 16 + qd * 4 + rg;
            float* orow = Ob + ((size_t)bh * S_ + row) * D_;
            #pragma unroll
            for (int nd = 0; nd < 8; ++nd)
                orow[nd * 16 + l15] = acc[mt][nd][rg];
        }
#undef STAGE
}

// ---- merge the two k-split partials ----------------------------------------
__global__ __launch_bounds__(256) void merge_kernel(
    float* __restrict__ O, const float* __restrict__ Op1,
    const float* __restrict__ L0, const float* __restrict__ L1)
{
    const int idx = blockIdx.x * 256 + threadIdx.x;   // float4 index
    const int row = idx >> 5;                          // bh*1024 + q
    const float inv = 1.f / (L0[row] + L1[row]);
    const float4 a = ((const float4*)O)[idx];
    const float4 b = ((const float4*)Op1)[idx];
    float4 o;
    o.x = (a.x + b.x) * inv; o.y = (a.y + b.y) * inv;
    o.z = (a.z + b.z) * inv; o.w = (a.w + b.w) * inv;
    ((float4*)O)[idx] = o;
}

extern "C" void kernel_launch(void* const* d_in, const int* in_sizes, int n_in,
                              void* d_out, int out_size, void* d_ws, size_t ws_size,
                              hipStream_t stream) {
    const float* Q = (const float*)d_in[0];
    const float* K = (const float*)d_in[1];
    const float* V = (const float*)d_in[2];
    const float* W = (const float*)d_in[3];
    float* O = (float*)d_out;

    // ws layout (~64.8 MB)
    unsigned short* Qp  = (unsigned short*)d_ws;                        // 6,389,760
    unsigned short* KhF = (unsigned short*)((char*)d_ws + 6389760);     // 37,748,736
    unsigned short* VhF = (unsigned short*)((char*)d_ws + 44138496);    // 6,291,456
    float*          Cr  = (float*)((char*)d_ws + 50429952);             // 1,572,864
    float*          Op1 = (float*)((char*)d_ws + 52002816);             // 12,582,912
    float*          L0  = (float*)((char*)d_ws + 64585728);             // 98,304
    float*          L1  = (float*)((char*)d_ws + 64684032);             // 98,304

    prep_kernel<<<dim3(NB_PREP), dim3(256), 0, stream>>>(Q, K, V, W, Qp, KhF, VhF, Cr);
    conv_attn_mfma<<<dim3(384), dim3(256), 0, stream>>>(Qp, KhF, VhF, Cr, O, Op1, L0, L1);
    merge_kernel<<<dim3(3072), dim3(256), 0, stream>>>(O, Op1, L0, L1);
}

// Round 5
// 296.765 us; speedup vs baseline: 1.2067x; 1.2067x over previous
//
#include <hip/hip_runtime.h>
#include <hip/hip_bf16.h>
#include <math.h>

#define B_ 2
#define H_ 12
#define S_ 1024
#define D_ 128
#define BH_ (B_ * H_)
#define SCALE 0.08838834764831843f

#define QPAD 16
#define QROWS (S_ + QPAD)          /* 1040 */

/* merged prepass grid segmentation */
#define NB_KH   768                /* 24 bh * 32 k-tiles */
#define NB_QP   3120               /* 24*1040*128 / 1024 */
#define NB_VT   3072               /* 24*32*4 */
#define NB_CORR 384                /* 24*16 */
#define NB_PREP (NB_KH + NB_QP + NB_VT + NB_CORR)

typedef __attribute__((ext_vector_type(8))) short short8;
typedef __attribute__((ext_vector_type(4))) float floatx4;

__device__ __forceinline__ unsigned short f2b(float f) {
    return __builtin_bit_cast(unsigned short, __float2bfloat16(f));
}

// ---- merged prepass ---------------------------------------------------------
// KH: Khat fragment-major. Block (bh*32+kt) is 24576 ushorts: [c24][nt2][ln64][e8]
//     Khat[k=kt*32+nt*16+(ln&15)][col=c*32+(ln>>4)*8+e]
//     Khat[k][i*128+d] = sum_j W[h][i][j]*SCALE * K[k+j-5][d].
//     No LDS: K tile (21.5 KB) is L1-resident, 50x reuse; stores coalesced 16B.
// QP: Q -> bf16 row-major, 16 zero rows of top padding.
// VT: VhF[bh*32+kt][nd8][ln64][e8] = V (sigma-permuted for swapped-MFMA PV).
// CORR: Corr[bh][q][d] = sum_{i,j: j-i>d} Ws[i,j]*(Q[q-5+i].K[q-5+i+(j-i-d)])
__global__ __launch_bounds__(256) void prep_kernel(
    const float* __restrict__ Q, const float* __restrict__ K,
    const float* __restrict__ V, const float* __restrict__ W,
    unsigned short* __restrict__ Qp, unsigned short* __restrict__ KhF,
    unsigned short* __restrict__ VhF, float* __restrict__ Corr)
{
    __shared__ union {
        float vt_ls[32][33];      /* 4224 B */
        float band[69][16];       /* 4416 B */
    } sm;
    const int blk = blockIdx.x;
    const int tid = threadIdx.x;

    if (blk < NB_KH) {
        const int bh = blk >> 5, kt = blk & 31;
        const int h = bh % H_;
        const int k0 = kt * 32;
        const float* Kb = K + (size_t)bh * S_ * D_;
        const float* Wh = W + h * 66;
        const size_t obase = (size_t)blk * 24576;
        for (int it = 0; it < 12; ++it) {
            const int idx = it * 2048 + tid * 8;   // output ushort index
            const int c   = idx >> 10;             // 0..23
            const int nt  = (idx >> 9) & 1;
            const int ln2 = (idx >> 3) & 63;
            const int i   = c >> 2;                // tap
            const int d0  = ((c & 3) << 5) | ((ln2 >> 4) << 3);
            const int k   = k0 + nt * 16 + (ln2 & 15);
            float a8[8];
            #pragma unroll
            for (int e = 0; e < 8; ++e) a8[e] = 0.f;
            #pragma unroll
            for (int j = 0; j < 11; ++j) {
                const int kr = k + j - 5;
                if (kr >= 0 && kr < S_) {
                    const float w = Wh[i * 11 + j];
                    const float4 v0 = *(const float4*)(Kb + (size_t)kr * D_ + d0);
                    const float4 v1 = *(const float4*)(Kb + (size_t)kr * D_ + d0 + 4);
                    a8[0] += w * v0.x; a8[1] += w * v0.y; a8[2] += w * v0.z; a8[3] += w * v0.w;
                    a8[4] += w * v1.x; a8[5] += w * v1.y; a8[6] += w * v1.z; a8[7] += w * v1.w;
                }
            }
            short8 o;
            #pragma unroll
            for (int e = 0; e < 8; ++e) o[e] = (short)f2b(a8[e] * SCALE);
            *(short8*)(KhF + obase + idx) = o;
        }
    } else if (blk < NB_KH + NB_QP) {
        const int idx = (blk - NB_KH) * 256 + tid;
        const size_t e0 = (size_t)idx * 4;
        const int bh = (int)(e0 / ((size_t)QROWS * D_));
        const int rem = (int)(e0 - (size_t)bh * QROWS * D_);
        const int r = rem / D_;
        const int d = rem - r * D_;
        const int sr = r - QPAD;
        float4 v = make_float4(0.f, 0.f, 0.f, 0.f);
        if (sr >= 0 && sr < S_)
            v = *(const float4*)(Q + ((size_t)bh * S_ + sr) * D_ + d);
        ushort4 o; o.x = f2b(v.x); o.y = f2b(v.y); o.z = f2b(v.z); o.w = f2b(v.w);
        *(ushort4*)(Qp + ((size_t)bh * QROWS + r) * D_ + d) = o;
    } else if (blk < NB_KH + NB_QP + NB_VT) {
        const int b2 = blk - (NB_KH + NB_QP);
        const int dt = b2 & 3, ktl = (b2 >> 2) & 31, bh = b2 >> 7;
        const int lk = tid >> 3, ld = (tid & 7) * 4;
        const float4 v4 = *(const float4*)(V + ((size_t)bh * S_ + ktl * 32 + lk) * D_ + dt * 32 + ld);
        sm.vt_ls[lk][ld + 0] = v4.x; sm.vt_ls[lk][ld + 1] = v4.y;
        sm.vt_ls[lk][ld + 2] = v4.z; sm.vt_ls[lk][ld + 3] = v4.w;
        __syncthreads();
        const int lk2 = tid >> 3, lc = (tid & 7) * 4;
        const int pb = ((lc >> 3) << 2) | (((lc >> 2) & 1) << 4);   // sigma
        const int d = dt * 32 + lk2;
        const int nd = d >> 4, l15v = d & 15;
        ushort4 o;
        o.x = f2b(sm.vt_ls[pb + 0][lk2]); o.y = f2b(sm.vt_ls[pb + 1][lk2]);
        o.z = f2b(sm.vt_ls[pb + 2][lk2]); o.w = f2b(sm.vt_ls[pb + 3][lk2]);
        const size_t addr = ((size_t)((bh * 32 + ktl) * 8 + nd) * 64
                             + (lc >> 3) * 16 + l15v) * 8 + (lc & 7);
        *(ushort4*)(VhF + addr) = o;
    } else {
        const int cb = blk - (NB_KH + NB_QP + NB_VT);
        const int bh = cb >> 4, q0c = (cb & 15) * 64;
        const int h = bh % H_;
        for (int s = tid; s < 69 * 16; s += 256) {
            const int r = s >> 4, dsl = s & 15;
            float v = 0.f;
            if (dsl < 10) {
                const int qp = q0c - 5 + r, delta = dsl + 1;
                if (qp >= 0 && qp + delta < S_) {
                    const float4* qr = (const float4*)(Q + ((size_t)bh * S_ + qp) * D_);
                    const float4* kr = (const float4*)(K + ((size_t)bh * S_ + qp + delta) * D_);
                    #pragma unroll 8
                    for (int c = 0; c < 32; ++c) {
                        const float4 a = qr[c], b = kr[c];
                        v += a.x * b.x + a.y * b.y + a.z * b.z + a.w * b.w;
                    }
                }
            }
            sm.band[r][dsl] = v;
        }
        __syncthreads();
        for (int e = tid; e < 64 * 16; e += 256) {
            const int ql = e >> 4, d = e & 15;
            float v = 0.f;
            if (d <= 10) {
                for (int i2 = 0; i2 < 6; ++i2)
                    for (int j = i2 + d + 1; j < 11; ++j)
                        v += W[h * 66 + i2 * 11 + j] * SCALE * sm.band[ql + i2][j - i2 - d - 1];
            }
            Corr[((size_t)bh << 14) + ((size_t)(q0c + ql) << 4) + d] = v;
        }
    }
}

// ---- main fused kernel ------------------------------------------------------
// 240 persistent blocks x 512 threads (8 waves). Wave owns 16 q-rows; Q frags
// register-resident (96 VGPR). Full 48 KB Khat k-tile double-buffered in LDS
// via global_load_lds, shared by all 8 waves (throughput-bound on LDS port).
// Work items (bh, qb, ks): heavy items alone, light items paired for balance.
__global__ __launch_bounds__(512, 2) void conv_attn_mfma(
    const unsigned short* __restrict__ Qp,   // [24][1040][128] bf16
    const unsigned short* __restrict__ KhF,  // fragment-major Khat
    const unsigned short* __restrict__ VhF,  // fragment-major permuted V
    const float* __restrict__ Corr,          // [24][1024][16]  f32
    float* __restrict__ O,                   // ks=0 partial (final out)
    float* __restrict__ Op1,                 // ks=1 partial
    float* __restrict__ L0, float* __restrict__ L1)  // [24*1024] row sums
{
    __shared__ __align__(16) unsigned short kb[2][24576];   // 96 KiB dbuf

    const int tid = threadIdx.x;
    const int wv = tid >> 6;        // 0..7
    const int ln = tid & 63;
    const int l15 = ln & 15;
    const int qd = ln >> 4;

    // 240 blocks = 8 XCD x 3 bh x 10 slots
    const int bid = blockIdx.x;
    const int slot = bid >> 3;                       // 0..29
    const int bh = (bid & 7) * 3 + slot / 10;
    const int r = slot % 10;

    const unsigned short* Khb = KhF + (size_t)(bh * 32) * 24576;
    const unsigned short* Vhb = VhF + (size_t)(bh * 32) * 4096 + ln * 8;
    const float* Cb = Corr + ((size_t)bh << 14);

#define STAGE(bi, ktile)                                                        \
    {                                                                           \
        const unsigned short* _s = Khb + (size_t)(ktile) * 24576 + wv * 3072 + ln * 8; \
        unsigned short* _d = &kb[bi][wv * 3072];                                \
        _Pragma("unroll")                                                       \
        for (int _g = 0; _g < 6; ++_g)                                          \
            __builtin_amdgcn_global_load_lds(                                   \
                (const __attribute__((address_space(1))) void*)(_s + _g * 512), \
                (__attribute__((address_space(3))) void*)(_d + _g * 512),       \
                16, 0, 0);                                                      \
    }

    const int nit = (r < 6) ? 2 : 1;
    for (int item = 0; item < nit; ++item) {
        int qb, ks;
        if (r < 6) { ks = r & 1; qb = (item == 0) ? (r >> 1) : (5 - (r >> 1)); }
        else       { ks = r & 1; qb = 6 + ((r - 6) >> 1); }

        const int qw0 = qb * 128 + wv * 16;      // wave's 16 q-rows
        const int ktw = 4 * qb + (wv >> 1);      // wave's last needed k-tile
        const int klo = ks * (2 * qb + 2);       // this split's first tile
        const int ntile = 2 * qb + 2;            // tiles in this split

        // ---- Q B-fragments: register-resident for the item ----------------
        short8 qf[6][4];
        {
            const unsigned short* qbase =
                Qp + ((size_t)bh * QROWS + qw0 + 11 + l15) * D_ + qd * 8;
            #pragma unroll
            for (int i = 0; i < 6; ++i)
                #pragma unroll
                for (int kc = 0; kc < 4; ++kc)
                    qf[i][kc] = *(const short8*)(qbase + (size_t)i * D_ + kc * 32);
        }

        floatx4 acc[8];
        #pragma unroll
        for (int nd = 0; nd < 8; ++nd) acc[nd] = (floatx4){0.f, 0.f, 0.f, 0.f};
        float l_run = 0.f;

        STAGE(0, klo);
        __syncthreads();   // tile 0 staged (barrier drains vmcnt)

        for (int t = 0; t < ntile; ++t) {
            const int kt = klo + t;
            if (t + 1 < ntile) STAGE((t + 1) & 1, kt + 1);

            if (kt <= ktw) {
                const int k0 = kt * 32;
                const unsigned short* A = &kb[t & 1][ln * 8];

                short8 vf[8];
                #pragma unroll
                for (int nd = 0; nd < 8; ++nd)
                    vf[nd] = *(const short8*)(Vhb + (size_t)kt * 4096 + nd * 512);

                floatx4 s0 = {0.f, 0.f, 0.f, 0.f}, s1 = {0.f, 0.f, 0.f, 0.f};
                #pragma unroll
                for (int c = 0; c < 24; ++c) {
                    const short8 a0 = *(const short8*)(A + c * 1024);
                    const short8 a1 = *(const short8*)(A + c * 1024 + 512);
                    const short8 b = qf[c >> 2][c & 3];
                    s0 = __builtin_amdgcn_mfma_f32_16x16x32_bf16(a0, b, s0, 0, 0, 0);
                    s1 = __builtin_amdgcn_mfma_f32_16x16x32_bf16(a1, b, s1, 0, 0, 0);
                }

                // ---- no-max softmax; lane l15 = q-row ---------------------
                const bool need_corr = (kt >= ktw - 1);
                const int qrow = qw0 + l15;
                float sum = 0.f;
                short8 pbv;
                #pragma unroll
                for (int nt = 0; nt < 2; ++nt)
                    #pragma unroll
                    for (int rg = 0; rg < 4; ++rg) {
                        const int kcol = k0 + nt * 16 + qd * 4 + rg;
                        float v = nt ? s1[rg] : s0[rg];
                        if (need_corr) {
                            const int dd = qrow - kcol;
                            if (dd >= 0 && dd <= 10) v -= Cb[(qrow << 4) + dd];
                        }
                        const float p = (kcol <= qrow) ? __expf(v) : 0.f;
                        sum += p;
                        pbv[nt * 4 + rg] = (short)f2b(p);
                    }
                sum += __shfl_xor(sum, 16);
                sum += __shfl_xor(sum, 32);
                l_run += sum;

                // ---- P @ V (pbv order matches sigma-permuted VhF) ---------
                #pragma unroll
                for (int nd = 0; nd < 8; ++nd)
                    acc[nd] = __builtin_amdgcn_mfma_f32_16x16x32_bf16(pbv, vf[nd], acc[nd], 0, 0, 0);
            }
            __syncthreads();   // next tile staged; buffer reuse safe
        }

        // ---- write this split's partial (unnormalized) --------------------
        float* Ob = ks ? Op1 : O;
        float* Lb = ks ? L1 : L0;
        if (qd == 0) Lb[bh * S_ + qw0 + l15] = l_run;
        #pragma unroll
        for (int rg = 0; rg < 4; ++rg) {
            const int row = qw0 + qd * 4 + rg;
            float* orow = Ob + ((size_t)bh * S_ + row) * D_;
            #pragma unroll
            for (int nd = 0; nd < 8; ++nd)
                orow[nd * 16 + l15] = acc[nd][rg];
        }
        __syncthreads();   // LDS safe before next item's STAGE
    }
#undef STAGE
}

// ---- merge the two k-split partials ----------------------------------------
__global__ __launch_bounds__(256) void merge_kernel(
    float* __restrict__ O, const float* __restrict__ Op1,
    const float* __restrict__ L0, const float* __restrict__ L1)
{
    const int idx = blockIdx.x * 256 + threadIdx.x;   // float4 index
    const int row = idx >> 5;                          // bh*1024 + q
    const float inv = 1.f / (L0[row] + L1[row]);
    const float4 a = ((const float4*)O)[idx];
    const float4 b = ((const float4*)Op1)[idx];
    float4 o;
    o.x = (a.x + b.x) * inv; o.y = (a.y + b.y) * inv;
    o.z = (a.z + b.z) * inv; o.w = (a.w + b.w) * inv;
    ((float4*)O)[idx] = o;
}

extern "C" void kernel_launch(void* const* d_in, const int* in_sizes, int n_in,
                              void* d_out, int out_size, void* d_ws, size_t ws_size,
                              hipStream_t stream) {
    const float* Q = (const float*)d_in[0];
    const float* K = (const float*)d_in[1];
    const float* V = (const float*)d_in[2];
    const float* W = (const float*)d_in[3];
    float* O = (float*)d_out;

    // ws layout (~64.8 MB)
    unsigned short* Qp  = (unsigned short*)d_ws;                        // 6,389,760
    unsigned short* KhF = (unsigned short*)((char*)d_ws + 6389760);     // 37,748,736
    unsigned short* VhF = (unsigned short*)((char*)d_ws + 44138496);    // 6,291,456
    float*          Cr  = (float*)((char*)d_ws + 50429952);             // 1,572,864
    float*          Op1 = (float*)((char*)d_ws + 52002816);             // 12,582,912
    float*          L0  = (float*)((char*)d_ws + 64585728);             // 98,304
    float*          L1  = (float*)((char*)d_ws + 64684032);             // 98,304

    prep_kernel<<<dim3(NB_PREP), dim3(256), 0, stream>>>(Q, K, V, W, Qp, KhF, VhF, Cr);
    conv_attn_mfma<<<dim3(240), dim3(512), 0, stream>>>(Qp, KhF, VhF, Cr, O, Op1, L0, L1);
    merge_kernel<<<dim3(3072), dim3(256), 0, stream>>>(O, Op1, L0, L1);
}

// Round 6
// 209.494 us; speedup vs baseline: 1.7094x; 1.4166x over previous
//
#include <hip/hip_runtime.h>
#include <hip/hip_bf16.h>
#include <math.h>

#define B_ 2
#define H_ 12
#define S_ 1024
#define D_ 128
#define BH_ (B_ * H_)
#define SCALE 0.08838834764831843f

#define QPAD 16
#define QROWS (S_ + QPAD)          /* 1040 */

/* prep_a grid segmentation */
#define NB_KH   768                /* 24 bh * 32 k-tiles */
#define NB_QP   3120               /* 24*1040*128 / 1024 */
#define NB_VT   3072               /* 24*32*4 */
#define NB_PREPA (NB_KH + NB_QP + NB_VT)

typedef __attribute__((ext_vector_type(8))) short short8;
typedef __attribute__((ext_vector_type(4))) float floatx4;

__device__ __forceinline__ unsigned short f2b(float f) {
    return __builtin_bit_cast(unsigned short, __float2bfloat16(f));
}

// ---- prep A: Khat fragments + Q pad/cvt + V permute -------------------------
// KH: Khat fragment-major. Block (bh*32+kt) is 24576 ushorts: [c24][nt2][ln64][e8]
//     Khat[k=kt*32+nt*16+(ln&15)][col=c*32+(ln>>4)*8+e]
//     Khat[k][i*128+d] = sum_j W[h][i][j]*SCALE * K[k+j-5][d].
//     K tile staged in padded LDS (coalesced); reads from LDS; coalesced stores.
// QP: Q -> bf16 row-major, 16 zero rows of top padding.
// VT: VhF[bh*32+kt][nd8][ln64][e8] = V (sigma-permuted for swapped-MFMA PV).
__global__ __launch_bounds__(256) void prep_a_kernel(
    const float* __restrict__ Q, const float* __restrict__ K,
    const float* __restrict__ V, const float* __restrict__ W,
    unsigned short* __restrict__ Qp, unsigned short* __restrict__ KhF,
    unsigned short* __restrict__ VhF)
{
    __shared__ __align__(16) union {
        float kld[42][132];       /* 22,176 B, padded: +4 floats/row */
        float vt_ls[32][33];
    } sm;
    const int blk = blockIdx.x;
    const int tid = threadIdx.x;

    if (blk < NB_KH) {
        const int bh = blk >> 5, kt = blk & 31;
        const int h = bh % H_;
        const int k0 = kt * 32;
        // stage K rows k0-5 .. k0+36 (zero OOB), coalesced
        for (int p = tid; p < 42 * 32; p += 256) {
            const int r = p >> 5, c4 = (p & 31) * 4;
            const int gk = k0 - 5 + r;
            float4 v = make_float4(0.f, 0.f, 0.f, 0.f);
            if (gk >= 0 && gk < S_)
                v = *(const float4*)(K + ((size_t)bh * S_ + gk) * D_ + c4);
            *(float4*)&sm.kld[r][c4] = v;
        }
        __syncthreads();
        const int wv = tid >> 6, ln = tid & 63;
        const float* Wh = W + h * 66;
        const size_t obase = (size_t)blk * 24576;
        #pragma unroll
        for (int nt = 0; nt < 2; ++nt) {
            const int lr = nt * 16 + (ln & 15);       // LDS row base (tap j adds)
            const int d0 = wv * 32 + (ln >> 4) * 8;   // col group (8 floats)
            float a[6][8];
            #pragma unroll
            for (int i = 0; i < 6; ++i)
                #pragma unroll
                for (int e = 0; e < 8; ++e) a[i][e] = 0.f;
            #pragma unroll
            for (int j = 0; j < 11; ++j) {
                const float4 v0 = *(const float4*)&sm.kld[lr + j][d0];
                const float4 v1 = *(const float4*)&sm.kld[lr + j][d0 + 4];
                #pragma unroll
                for (int i = 0; i < 6; ++i) {
                    const float w = Wh[i * 11 + j];
                    a[i][0] += w * v0.x; a[i][1] += w * v0.y;
                    a[i][2] += w * v0.z; a[i][3] += w * v0.w;
                    a[i][4] += w * v1.x; a[i][5] += w * v1.y;
                    a[i][6] += w * v1.z; a[i][7] += w * v1.w;
                }
            }
            #pragma unroll
            for (int i = 0; i < 6; ++i) {
                short8 o;
                #pragma unroll
                for (int e = 0; e < 8; ++e) o[e] = (short)f2b(a[i][e] * SCALE);
                // c = i*4 + wv ; coalesced 16B/lane store
                *(short8*)(KhF + obase + (size_t)(((i * 4 + wv) * 2 + nt) * 64 + ln) * 8) = o;
            }
        }
    } else if (blk < NB_KH + NB_QP) {
        const int idx = (blk - NB_KH) * 256 + tid;
        const size_t e0 = (size_t)idx * 4;
        const int bh = (int)(e0 / ((size_t)QROWS * D_));
        const int rem = (int)(e0 - (size_t)bh * QROWS * D_);
        const int r = rem / D_;
        const int d = rem - r * D_;
        const int sr = r - QPAD;
        float4 v = make_float4(0.f, 0.f, 0.f, 0.f);
        if (sr >= 0 && sr < S_)
            v = *(const float4*)(Q + ((size_t)bh * S_ + sr) * D_ + d);
        ushort4 o; o.x = f2b(v.x); o.y = f2b(v.y); o.z = f2b(v.z); o.w = f2b(v.w);
        *(ushort4*)(Qp + ((size_t)bh * QROWS + r) * D_ + d) = o;
    } else {
        const int b2 = blk - (NB_KH + NB_QP);
        const int dt = b2 & 3, ktl = (b2 >> 2) & 31, bh = b2 >> 7;
        const int lk = tid >> 3, ld = (tid & 7) * 4;
        const float4 v4 = *(const float4*)(V + ((size_t)bh * S_ + ktl * 32 + lk) * D_ + dt * 32 + ld);
        sm.vt_ls[lk][ld + 0] = v4.x; sm.vt_ls[lk][ld + 1] = v4.y;
        sm.vt_ls[lk][ld + 2] = v4.z; sm.vt_ls[lk][ld + 3] = v4.w;
        __syncthreads();
        const int lk2 = tid >> 3, lc = (tid & 7) * 4;
        const int pb = ((lc >> 3) << 2) | (((lc >> 2) & 1) << 4);   // sigma
        const int d = dt * 32 + lk2;
        const int nd = d >> 4, l15v = d & 15;
        ushort4 o;
        o.x = f2b(sm.vt_ls[pb + 0][lk2]); o.y = f2b(sm.vt_ls[pb + 1][lk2]);
        o.z = f2b(sm.vt_ls[pb + 2][lk2]); o.w = f2b(sm.vt_ls[pb + 3][lk2]);
        const size_t addr = ((size_t)((bh * 32 + ktl) * 8 + nd) * 64
                             + (lc >> 3) * 16 + l15v) * 8 + (lc & 7);
        *(ushort4*)(VhF + addr) = o;
    }
}

// ---- prep B: causal-band correction table ----------------------------------
// Corr[bh][q][d] = sum_{i,j: j-i>d} Ws[i,j]*(Q[q-5+i].K[q-5+i+(j-i-d)])
// Q/K row panels staged in LDS; band dots read LDS (no scattered global reads).
__global__ __launch_bounds__(256) void prep_corr_kernel(
    const float* __restrict__ Q, const float* __restrict__ K,
    const float* __restrict__ W, float* __restrict__ Corr)
{
    __shared__ __align__(16) struct {
        float Qs[69][132];        /* rows q0c-5 .. q0c+63 */
        float Ks[78][132];        /* rows q0c-4 .. q0c+73 */
        float band[69][16];
    } sm;
    const int cb = blockIdx.x;
    const int tid = threadIdx.x;
    const int bh = cb >> 4, q0c = (cb & 15) * 64;
    const int h = bh % H_;

    for (int p = tid; p < 69 * 32; p += 256) {
        const int r = p >> 5, c4 = (p & 31) * 4;
        const int gq = q0c - 5 + r;
        float4 v = make_float4(0.f, 0.f, 0.f, 0.f);
        if (gq >= 0 && gq < S_)
            v = *(const float4*)(Q + ((size_t)bh * S_ + gq) * D_ + c4);
        *(float4*)&sm.Qs[r][c4] = v;
    }
    for (int p = tid; p < 78 * 32; p += 256) {
        const int r = p >> 5, c4 = (p & 31) * 4;
        const int gk = q0c - 4 + r;
        float4 v = make_float4(0.f, 0.f, 0.f, 0.f);
        if (gk >= 0 && gk < S_)
            v = *(const float4*)(K + ((size_t)bh * S_ + gk) * D_ + c4);
        *(float4*)&sm.Ks[r][c4] = v;
    }
    __syncthreads();
    // band[r][dsl] = Q[q0c-5+r] . K[q0c-5+r + dsl+1]  (= Qs[r] . Ks[r+dsl])
    for (int s = tid; s < 69 * 16; s += 256) {
        const int r = s >> 4, dsl = s & 15;
        float v = 0.f;
        if (dsl < 10) {
            const float4* qr = (const float4*)&sm.Qs[r][0];
            const float4* kr = (const float4*)&sm.Ks[r + dsl][0];
            #pragma unroll 8
            for (int c = 0; c < 32; ++c) {
                const float4 a = qr[c], b = kr[c];
                v += a.x * b.x + a.y * b.y + a.z * b.z + a.w * b.w;
            }
        }
        sm.band[r][dsl] = v;
    }
    __syncthreads();
    for (int e = tid; e < 64 * 16; e += 256) {
        const int ql = e >> 4, d = e & 15;
        float v = 0.f;
        if (d <= 10) {
            for (int i2 = 0; i2 < 6; ++i2)
                for (int j = i2 + d + 1; j < 11; ++j)
                    v += W[h * 66 + i2 * 11 + j] * SCALE * sm.band[ql + i2][j - i2 - d - 1];
        }
        Corr[((size_t)bh << 14) + ((size_t)(q0c + ql) << 4) + d] = v;
    }
}

// ---- main fused kernel ------------------------------------------------------
// 480 blocks x 256 threads. No LDS, no barriers: every MFMA operand load is a
// coalesced 1KB global read (KhF/VhF fragment-major, L2-resident per XCD).
// Waves free-run; no-max softmax -> partials are plain sums; merge combines
// the 2 k-splits. Work items (bh,qb,ks): heavy alone, light paired.
__global__ __launch_bounds__(256, 2) void conv_attn_mfma(
    const unsigned short* __restrict__ Qp,   // [24][1040][128] bf16
    const unsigned short* __restrict__ KhF,  // fragment-major Khat
    const unsigned short* __restrict__ VhF,  // fragment-major permuted V
    const float* __restrict__ Corr,          // [24][1024][16]  f32
    float* __restrict__ O,                   // ks=0 partial (final out)
    float* __restrict__ Op1,                 // ks=1 partial
    float* __restrict__ L0, float* __restrict__ L1)  // [24*1024] row sums
{
    const int tid = threadIdx.x;
    const int wv = tid >> 6;        // 0..3
    const int ln = tid & 63;
    const int l15 = ln & 15;
    const int qd = ln >> 4;

    // 480 blocks = 8 XCD x 3 bh x 20 slots (bh's Khat lives in one XCD L2)
    const int bid = blockIdx.x;
    const int slot = bid >> 3;                       // 0..59
    const int bh = (bid & 7) * 3 + slot / 20;
    const int r20 = slot % 20;
    const int r = r20 >> 1;                          // item slot 0..9
    const int half = r20 & 1;                        // which 64-row half

    const unsigned short* Khb = KhF + (size_t)(bh * 32) * 24576 + ln * 8;
    const unsigned short* Vhb = VhF + (size_t)(bh * 32) * 4096 + ln * 8;
    const float* Cb = Corr + ((size_t)bh << 14);

    const int nit = (r < 6) ? 2 : 1;
    for (int item = 0; item < nit; ++item) {
        int qb, ks;
        if (r < 6) { ks = r & 1; qb = (item == 0) ? (r >> 1) : (5 - (r >> 1)); }
        else       { ks = r & 1; qb = 6 + ((r - 6) >> 1); }

        const int wl = half * 4 + wv;            // logical wave 0..7
        const int qw0 = qb * 128 + wl * 16;      // wave's 16 q-rows
        const int ktw = 4 * qb + (wl >> 1);      // wave's last needed k-tile
        const int klo = ks * (2 * qb + 2);       // this split's first tile
        const int ntile = 2 * qb + 2;            // tiles in this split

        // ---- Q B-fragments: register-resident for the item ----------------
        short8 qf[6][4];
        {
            const unsigned short* qbase =
                Qp + ((size_t)bh * QROWS + qw0 + 11 + l15) * D_ + qd * 8;
            #pragma unroll
            for (int i = 0; i < 6; ++i)
                #pragma unroll
                for (int kc = 0; kc < 4; ++kc)
                    qf[i][kc] = *(const short8*)(qbase + (size_t)i * D_ + kc * 32);
        }

        floatx4 acc[8];
        #pragma unroll
        for (int nd = 0; nd < 8; ++nd) acc[nd] = (floatx4){0.f, 0.f, 0.f, 0.f};
        float l_run = 0.f;

        for (int t = 0; t < ntile; ++t) {
            const int kt = klo + t;
            if (kt > ktw) break;                 // waves independent
            const int k0 = kt * 32;
            const unsigned short* A = Khb + (size_t)kt * 24576;

            short8 vf[8];
            #pragma unroll
            for (int nd = 0; nd < 8; ++nd)
                vf[nd] = *(const short8*)(Vhb + (size_t)kt * 4096 + nd * 512);

            floatx4 s0 = {0.f, 0.f, 0.f, 0.f}, s1 = {0.f, 0.f, 0.f, 0.f};
            #pragma unroll
            for (int c = 0; c < 24; ++c) {
                const short8 a0 = *(const short8*)(A + c * 1024);
                const short8 a1 = *(const short8*)(A + c * 1024 + 512);
                const short8 b = qf[c >> 2][c & 3];
                s0 = __builtin_amdgcn_mfma_f32_16x16x32_bf16(a0, b, s0, 0, 0, 0);
                s1 = __builtin_amdgcn_mfma_f32_16x16x32_bf16(a1, b, s1, 0, 0, 0);
            }

            // ---- no-max softmax; lane l15 = q-row -------------------------
            const bool need_corr = (kt >= ktw - 1);
            const int qrow = qw0 + l15;
            float sum = 0.f;
            short8 pbv;
            #pragma unroll
            for (int nt = 0; nt < 2; ++nt)
                #pragma unroll
                for (int rg = 0; rg < 4; ++rg) {
                    const int kcol = k0 + nt * 16 + qd * 4 + rg;
                    float v = nt ? s1[rg] : s0[rg];
                    if (need_corr) {
                        const int dd = qrow - kcol;
                        if (dd >= 0 && dd <= 10) v -= Cb[(qrow << 4) + dd];
                    }
                    const float p = (kcol <= qrow) ? __expf(v) : 0.f;
                    sum += p;
                    pbv[nt * 4 + rg] = (short)f2b(p);
                }
            sum += __shfl_xor(sum, 16);
            sum += __shfl_xor(sum, 32);
            l_run += sum;

            // ---- P @ V (pbv order matches sigma-permuted VhF) -------------
            #pragma unroll
            for (int nd = 0; nd < 8; ++nd)
                acc[nd] = __builtin_amdgcn_mfma_f32_16x16x32_bf16(pbv, vf[nd], acc[nd], 0, 0, 0);
        }

        // ---- write this split's partial (unnormalized) --------------------
        float* Ob = ks ? Op1 : O;
        float* Lb = ks ? L1 : L0;
        if (qd == 0) Lb[bh * S_ + qw0 + l15] = l_run;
        #pragma unroll
        for (int rg = 0; rg < 4; ++rg) {
            const int row = qw0 + qd * 4 + rg;
            float* orow = Ob + ((size_t)bh * S_ + row) * D_;
            #pragma unroll
            for (int nd = 0; nd < 8; ++nd)
                orow[nd * 16 + l15] = acc[nd][rg];
        }
    }
}

// ---- merge the two k-split partials ----------------------------------------
__global__ __launch_bounds__(256) void merge_kernel(
    float* __restrict__ O, const float* __restrict__ Op1,
    const float* __restrict__ L0, const float* __restrict__ L1)
{
    const int idx = blockIdx.x * 256 + threadIdx.x;   // float4 index
    const int row = idx >> 5;                          // bh*1024 + q
    const float inv = 1.f / (L0[row] + L1[row]);
    const float4 a = ((const float4*)O)[idx];
    const float4 b = ((const float4*)Op1)[idx];
    float4 o;
    o.x = (a.x + b.x) * inv; o.y = (a.y + b.y) * inv;
    o.z = (a.z + b.z) * inv; o.w = (a.w + b.w) * inv;
    ((float4*)O)[idx] = o;
}

extern "C" void kernel_launch(void* const* d_in, const int* in_sizes, int n_in,
                              void* d_out, int out_size, void* d_ws, size_t ws_size,
                              hipStream_t stream) {
    const float* Q = (const float*)d_in[0];
    const float* K = (const float*)d_in[1];
    const float* V = (const float*)d_in[2];
    const float* W = (const float*)d_in[3];
    float* O = (float*)d_out;

    // ws layout (~64.8 MB)
    unsigned short* Qp  = (unsigned short*)d_ws;                        // 6,389,760
    unsigned short* KhF = (unsigned short*)((char*)d_ws + 6389760);     // 37,748,736
    unsigned short* VhF = (unsigned short*)((char*)d_ws + 44138496);    // 6,291,456
    float*          Cr  = (float*)((char*)d_ws + 50429952);             // 1,572,864
    float*          Op1 = (float*)((char*)d_ws + 52002816);             // 12,582,912
    float*          L0  = (float*)((char*)d_ws + 64585728);             // 98,304
    float*          L1  = (float*)((char*)d_ws + 64684032);             // 98,304

    prep_a_kernel<<<dim3(NB_PREPA), dim3(256), 0, stream>>>(Q, K, V, W, Qp, KhF, VhF);
    prep_corr_kernel<<<dim3(384), dim3(256), 0, stream>>>(Q, K, W, Cr);
    conv_attn_mfma<<<dim3(480), dim3(256), 0, stream>>>(Qp, KhF, VhF, Cr, O, Op1, L0, L1);
    merge_kernel<<<dim3(3072), dim3(256), 0, stream>>>(O, Op1, L0, L1);
}